// Round 4
// baseline (81.734 us; speedup 1.0000x reference)
//
#include <hip/hip_runtime.h>

// LS2T iterated sums (ORDER=3): B=64, T=4096, D=128, F=64, C=6.
// m_c(t,f) = seq[b,t,:]·kernel[c,:,f] + bias[c,f]
// Y1 = sum m0; Y2 = sum m2*cumx(m1); Y3 = sum m5*cumx(m4*cumx(m3))
//
// Round 4: component-split wave groups (cg0: c=0..2 scans Y1/Y2; cg1: c=3..5
// scans Y3) with B-fragments in REGISTERS (48 VGPR) -> no kernel tile in LDS.
// LDS = 3-buffer ring of 32-t seq chunks (24 KB). 512 thr, launch_bounds
// (512,4) targets <=128 VGPR -> 4 waves/SIMD, 2 blocks/CU. One barrier per
// chunk; loads prefetched 2 chunks ahead through two static register sets.

#define B_ 64
#define T_ 4096
#define D_ 128
#define F_ 64
#define TGROUPS 8          // blocks per batch; each owns 512 t
#define TB 512
#define CH 32              // t per chunk
#define NITER (TB / CH)    // 16
#define TPB 512

typedef __attribute__((ext_vector_type(8))) short short8v;
typedef __attribute__((ext_vector_type(4))) float f32x4;
typedef __attribute__((ext_vector_type(4))) unsigned short ushort4v;

__device__ __forceinline__ unsigned short f2bf(float x) {
    unsigned u = __float_as_uint(x);
    unsigned r = u + 0x7FFFu + ((u >> 16) & 1u);   // RNE
    return (unsigned short)(r >> 16);
}

__device__ __forceinline__ int swzkey(int row) {   // row in [0,32)
    return (row & 3) | (((row >> 3) & 3) << 2);
}

__global__ __launch_bounds__(TPB, 4)
void ls2t_kernel(const float* __restrict__ seq,
                 const float* __restrict__ kern,
                 const float* __restrict__ bias,
                 float* __restrict__ ws)
{
    __shared__ unsigned short slds[3][CH * D_];    // 3 x 8 KB ring

    const int tid  = threadIdx.x;
    const int tg   = blockIdx.x;
    const int b    = blockIdx.y;
    const int lane = tid & 63;
    const int w    = tid >> 6;
    const int cg   = w >> 2;       // component group: 0 -> c0..2, 1 -> c3..5
    const int wv   = w & 3;        // f-range of this wave
    const int fr   = lane & 15;
    const int lg   = lane >> 4;
    const int f    = wv * 16 + fr;

    // ---- B fragments in registers: bfrag[cc][ks] covers d = ks*32+lg*8..+8
    // (mfma B layout: col = lane&15 = f, k = (lane>>4)*8 + j)
    short8v bfrag[3][4];
    float bc[3];
    #pragma unroll
    for (int cc = 0; cc < 3; ++cc) {
        const int c = cg * 3 + cc;
        bc[cc] = bias[c * F_ + f];
        #pragma unroll
        for (int ks = 0; ks < 4; ++ks) {
            const float* kp = kern + ((size_t)c * D_ + ks * 32 + lg * 8) * F_ + f;
            short8v bf;
            #pragma unroll
            for (int j = 0; j < 8; ++j) bf[j] = (short)f2bf(kp[(size_t)j * F_]);
            bfrag[cc][ks] = bf;
        }
    }

    const float* sbase = seq + ((size_t)b * T_ + (size_t)tg * TB) * D_;

    // staging map: phys row p (0..31) of chunk i holds t_local =
    // (p>>3)*128 + i*8 + (p&7)  -> lane-group lg owns contiguous t-stripe
    // [lg*128, lg*128+128) across the 16 chunks.
    auto issue = [&](int i, float4* v) {
        #pragma unroll
        for (int k = 0; k < 2; ++k) {
            int p = k * TPB + tid;
            int row = p >> 5, c4 = p & 31;
            int tl = ((row >> 3) * 128) + i * 8 + (row & 7);
            v[k] = *(reinterpret_cast<const float4*>(sbase + (size_t)tl * D_) + c4);
        }
    };
    auto wlds = [&](int bufi, const float4* v) {
        #pragma unroll
        for (int k = 0; k < 2; ++k) {
            int p = k * TPB + tid;
            int row = p >> 5, c4 = p & 31;
            ushort4v w4;
            w4[0] = f2bf(v[k].x); w4[1] = f2bf(v[k].y);
            w4[2] = f2bf(v[k].z); w4[3] = f2bf(v[k].w);
            int idx = (row * D_ + c4 * 4) ^ (swzkey(row) << 3);
            *reinterpret_cast<ushort4v*>(&slds[bufi][idx]) = w4;
        }
    };

    // scan states (only this cg's fields are live)
    float a0 = 0.f, s1 = 0.f, s2 = 0.f, q2 = 0.f;                    // cg0
    float su = 0.f, sv = 0.f, sw = 0.f, qvu = 0.f, qwv = 0.f, qwvu = 0.f; // cg1

    auto compute = [&](int bufi) {
        f32x4 acc[3][2];
        #pragma unroll
        for (int cc = 0; cc < 3; ++cc)
            #pragma unroll
            for (int tf = 0; tf < 2; ++tf)
                acc[cc][tf] = (f32x4){bc[cc], bc[cc], bc[cc], bc[cc]};

        #pragma unroll
        for (int ks = 0; ks < 4; ++ks) {
            const int d0 = ks * 32 + lg * 8;
            short8v a[2];
            #pragma unroll
            for (int tf = 0; tf < 2; ++tf) {
                int vrow = (fr >> 2) * 8 + tf * 4 + (fr & 3);
                a[tf] = *reinterpret_cast<const short8v*>(
                    &slds[bufi][(vrow * D_ + d0) ^ (swzkey(vrow) << 3)]);
            }
            #pragma unroll
            for (int cc = 0; cc < 3; ++cc)
                #pragma unroll
                for (int tf = 0; tf < 2; ++tf)
                    acc[cc][tf] = __builtin_amdgcn_mfma_f32_16x16x32_bf16(
                        a[tf], bfrag[cc][ks], acc[cc][tf], 0, 0, 0);
        }

        // lane owns t = tg*512 + lg*128 + i*8 + (tf*4 + r): chain in-lane
        if (cg == 0) {
            #pragma unroll
            for (int tf = 0; tf < 2; ++tf)
                #pragma unroll
                for (int r = 0; r < 4; ++r) {
                    float m0 = acc[0][tf][r], m1 = acc[1][tf][r], m2 = acc[2][tf][r];
                    a0 += m0;
                    q2  = fmaf(m2, s1, q2);   // s1 = exclusive cumsum(m1)
                    s2 += m2;
                    s1 += m1;
                }
        } else {
            #pragma unroll
            for (int tf = 0; tf < 2; ++tf)
                #pragma unroll
                for (int r = 0; r < 4; ++r) {
                    float m3 = acc[0][tf][r], m4 = acc[1][tf][r], m5 = acc[2][tf][r];
                    qwvu = fmaf(m5, qvu, qwvu);
                    qwv  = fmaf(m5, sv, qwv);
                    sw  += m5;
                    qvu  = fmaf(m4, su, qvu);
                    sv  += m4;
                    su  += m3;
                }
        }
    };

    // ---- pipeline: prologue stages chunk0; 2-ahead reg prefetch, ring-3 LDS
    float4 vA[2], vB[2];
    issue(0, vA);
    issue(1, vB);
    wlds(0, vA);
    __syncthreads();

    #pragma unroll 1
    for (int i = 0; i < NITER; i += 2) {
        if (i + 2 < NITER) issue(i + 2, vA);
        wlds((i + 1) % 3, vB);
        __syncthreads();
        compute(i % 3);

        if (i + 3 < NITER) issue(i + 3, vB);
        if (i + 2 < NITER) wlds((i + 2) % 3, vA);
        __syncthreads();
        compute((i + 1) % 3);
    }

    // ---- merge the 4 lane-group stripes (time order: lg ascending) ----
    if (cg == 0) {
        #pragma unroll
        for (int m = 16; m <= 32; m <<= 1) {
            float oa0 = __shfl_xor(a0, m), os1 = __shfl_xor(s1, m);
            float os2 = __shfl_xor(s2, m), oq2 = __shfl_xor(q2, m);
            bool up = (lane & m) != 0;
            float Aa0 = up ? oa0 : a0, As1 = up ? os1 : s1;
            float As2 = up ? os2 : s2, Aq2 = up ? oq2 : q2;
            float Ba0 = up ? a0 : oa0, Bs1 = up ? s1 : os1;
            float Bs2 = up ? s2 : os2, Bq2 = up ? q2 : oq2;
            a0 = Aa0 + Ba0;
            q2 = Aq2 + Bq2 + As1 * Bs2;
            s1 = As1 + Bs1;
            s2 = As2 + Bs2;
        }
        if (lg == 0) {
            float* wp = ws + (((size_t)b * TGROUPS + tg) * F_ + f) * 10;
            wp[0] = a0; wp[1] = s1; wp[2] = s2; wp[3] = q2;
        }
    } else {
        #pragma unroll
        for (int m = 16; m <= 32; m <<= 1) {
            float osu = __shfl_xor(su, m),  osv = __shfl_xor(sv, m);
            float osw = __shfl_xor(sw, m),  oqvu = __shfl_xor(qvu, m);
            float oqwv = __shfl_xor(qwv, m), oqwvu = __shfl_xor(qwvu, m);
            bool up = (lane & m) != 0;
            float Asu = up ? osu : su,   Asv = up ? osv : sv;
            float Asw = up ? osw : sw,   Aqvu = up ? oqvu : qvu;
            float Aqwv = up ? oqwv : qwv, Aqwvu = up ? oqwvu : qwvu;
            float Bsu = up ? su : osu,   Bsv = up ? sv : osv;
            float Bsw = up ? sw : osw,   Bqvu = up ? qvu : oqvu;
            float Bqwv = up ? qwv : oqwv, Bqwvu = up ? qwvu : oqwvu;
            qwvu = Aqwvu + Bqwvu + Aqvu * Bsw + Asu * Bqwv;
            qwv  = Aqwv + Bqwv + Asv * Bsw;
            qvu  = Aqvu + Bqvu + Asu * Bsv;
            su = Asu + Bsu;
            sv = Asv + Bsv;
            sw = Asw + Bsw;
        }
        if (lg == 0) {
            float* wp = ws + (((size_t)b * TGROUPS + tg) * F_ + f) * 10;
            wp[4] = su; wp[5] = sv; wp[6] = sw;
            wp[7] = qvu; wp[8] = qwv; wp[9] = qwvu;
        }
    }
}

struct St { float a0, s1, s2, q2, su, sv, sw, qvu, qwv, qwvu; };

__device__ __forceinline__ St mergeSt(const St& A, const St& B) {
    St r;
    r.a0   = A.a0 + B.a0;
    r.q2   = A.q2 + B.q2 + A.s1 * B.s2;
    r.s1   = A.s1 + B.s1;
    r.s2   = A.s2 + B.s2;
    r.qwvu = A.qwvu + B.qwvu + A.qvu * B.sw + A.su * B.qwv;
    r.qwv  = A.qwv + B.qwv + A.sv * B.sw;
    r.qvu  = A.qvu + B.qvu + A.su * B.sv;
    r.su   = A.su + B.su;
    r.sv   = A.sv + B.sv;
    r.sw   = A.sw + B.sw;
    return r;
}

__global__ __launch_bounds__(64)
void ls2t_fold_kernel(const float* __restrict__ ws, float* __restrict__ out)
{
    const int b = blockIdx.x;
    const int f = threadIdx.x;
    St A = {0, 0, 0, 0, 0, 0, 0, 0, 0, 0};
    #pragma unroll
    for (int g = 0; g < TGROUPS; ++g) {
        const float* rp = ws + (((size_t)b * TGROUPS + g) * F_ + f) * 10;
        St r = {rp[0], rp[1], rp[2], rp[3], rp[4],
                rp[5], rp[6], rp[7], rp[8], rp[9]};
        A = mergeSt(A, r);
    }
    float* op = out + ((size_t)b * F_ + f) * 3;
    op[0] = A.a0;
    op[1] = A.q2;
    op[2] = A.qwvu;
}

extern "C" void kernel_launch(void* const* d_in, const int* in_sizes, int n_in,
                              void* d_out, int out_size, void* d_ws, size_t ws_size,
                              hipStream_t stream) {
    const float* seq  = (const float*)d_in[0];
    const float* kern = (const float*)d_in[1];
    const float* bias = (const float*)d_in[2];
    float* out = (float*)d_out;
    float* ws  = (float*)d_ws;   // B_*TGROUPS*F_*10*4 = 1.31 MB

    dim3 g1(TGROUPS, B_);        // 512 blocks -> 2 per CU
    ls2t_kernel<<<g1, TPB, 0, stream>>>(seq, kern, bias, ws);
    ls2t_fold_kernel<<<B_, F_, 0, stream>>>(ws, out);
}

// Round 5
// 47.925 us; speedup vs baseline: 1.7054x; 1.7054x over previous
//
#include <hip/hip_runtime.h>
#include <hip/hip_bf16.h>

// LS2T iterated sums (ORDER=3): B=64, T=4096, D=128, F=64, C=6.
// m_c(t,f) = seq[b,t,:]·kernel[c,:,f] + bias[c,f]
// Y1 = sum m0; Y2 = sum m2*cumx(m1); Y3 = sum m5*cumx(m4*cumx(m3))
//
// Round 5: component-split waves (cg0: c0..2 -> Y1,Y2; cg1: c3..5 -> Y3),
// B-fragments in registers (48 VGPR). LDS = ring-3 of 16-t bf16 chunks
// (12 KB total), XOR-swizzled for conflict-free ds_read_b128. No-drain
// barriers (lgkmcnt only) keep 2-chunk-ahead global prefetch in flight.
// launch_bounds(512,2): no register cap -> no scratch spills.

#define B_ 64
#define T_ 4096
#define D_ 128
#define F_ 64
#define TGROUPS 8          // blocks per batch; each owns 512 t
#define TB 512
#define CHT 16             // t per chunk
#define NITER (TB / CHT)   // 32
#define TPB 512
#define RING 3

typedef __attribute__((ext_vector_type(8))) short short8v;
typedef __attribute__((ext_vector_type(4))) float f32x4;
typedef __attribute__((ext_vector_type(4))) unsigned short ushort4v;

__device__ __forceinline__ unsigned short bfb(float x) {
    __hip_bfloat16 h = __float2bfloat16(x);   // RNE
    unsigned short u;
    __builtin_memcpy(&u, &h, 2);
    return u;
}

// barrier WITHOUT vmcnt drain: waits only LDS ops, keeps global loads in flight
#define BAR() asm volatile("s_waitcnt lgkmcnt(0)\n\ts_barrier" ::: "memory")

__global__ __launch_bounds__(TPB, 2)
void ls2t_kernel(const float* __restrict__ seq,
                 const float* __restrict__ kern,
                 const float* __restrict__ bias,
                 float* __restrict__ ws)
{
    __shared__ unsigned short slds[RING][CHT * D_];   // 3 x 4 KB bf16

    const int tid  = threadIdx.x;
    const int tg   = blockIdx.x;
    const int b    = blockIdx.y;
    const int lane = tid & 63;
    const int w    = tid >> 6;
    const int cg   = w >> 2;       // 0 -> c0..2, 1 -> c3..5
    const int wv   = w & 3;        // f-range of this wave
    const int fr   = lane & 15;
    const int lg   = lane >> 4;
    const int f    = wv * 16 + fr;

    // ---- B fragments in registers (mfma B: col=lane&15=f, k=(lane>>4)*8+j)
    short8v bfrag[3][4];
    float bc[3];
    #pragma unroll
    for (int cc = 0; cc < 3; ++cc) {
        const int c = cg * 3 + cc;
        bc[cc] = bias[c * F_ + f];
        #pragma unroll
        for (int ks = 0; ks < 4; ++ks) {
            const float* kp = kern + ((size_t)c * D_ + ks * 32 + lg * 8) * F_ + f;
            short8v bf;
            #pragma unroll
            for (int j = 0; j < 8; ++j) bf[j] = (short)bfb(kp[(size_t)j * F_]);
            bfrag[cc][ks] = bf;
        }
    }

    const float* sbase = seq + ((size_t)b * T_ + (size_t)tg * TB) * D_;

    // staging: thread -> (row srow 0..15, float4-index c4 0..31) of the chunk.
    // chunk row r holds t_local = (r>>2)*128 + i*4 + (r&3)  (lane-group lg
    // owns contiguous t-stripe [lg*128, +128) across the 32 chunks).
    // LDS 16B block jb of row r contains global d-block (jb ^ (r&7)).
    const int srow = tid >> 5;
    const int c4   = tid & 31;
    const int skey = srow & 7;
    const float* g0 = sbase + ((size_t)((srow >> 2) * 128 + (srow & 3))) * D_ + c4 * 4;
    const int woff = srow * D_ + 8 * ((c4 >> 1) ^ skey) + 4 * (c4 & 1);  // shorts

    float4 vA, vB;

    auto issueA = [&](int i) { vA = *reinterpret_cast<const float4*>(g0 + (size_t)i * 4 * D_); };
    auto issueB = [&](int i) { vB = *reinterpret_cast<const float4*>(g0 + (size_t)i * 4 * D_); };
    auto wldsA = [&](int bufi) {
        ushort4v u;
        u[0] = bfb(vA.x); u[1] = bfb(vA.y); u[2] = bfb(vA.z); u[3] = bfb(vA.w);
        *reinterpret_cast<ushort4v*>(&slds[bufi][woff]) = u;
    };
    auto wldsB = [&](int bufi) {
        ushort4v u;
        u[0] = bfb(vB.x); u[1] = bfb(vB.y); u[2] = bfb(vB.z); u[3] = bfb(vB.w);
        *reinterpret_cast<ushort4v*>(&slds[bufi][woff]) = u;
    };

    // scan states (only this cg's half is live per wave)
    float a0 = 0.f, s1 = 0.f, s2 = 0.f, q2 = 0.f;
    float su = 0.f, sv = 0.f, sw = 0.f, qvu = 0.f, qwv = 0.f, qwvu = 0.f;

    auto compute = [&](int bufi) {
        f32x4 acc[3];
        #pragma unroll
        for (int cc = 0; cc < 3; ++cc)
            acc[cc] = (f32x4){bc[cc], bc[cc], bc[cc], bc[cc]};

        #pragma unroll
        for (int ks = 0; ks < 4; ++ks) {
            const int m0i = ks * 4 + lg;
            short8v a = *reinterpret_cast<const short8v*>(
                &slds[bufi][fr * D_ + 8 * (m0i ^ (fr & 7))]);
            #pragma unroll
            for (int cc = 0; cc < 3; ++cc)
                acc[cc] = __builtin_amdgcn_mfma_f32_16x16x32_bf16(
                    a, bfrag[cc][ks], acc[cc], 0, 0, 0);
        }

        // lane owns t = tg*512 + lg*128 + i*4 + r  -> chain in-lane
        if (cg == 0) {
            #pragma unroll
            for (int r = 0; r < 4; ++r) {
                float m0 = acc[0][r], m1 = acc[1][r], m2 = acc[2][r];
                a0 += m0;
                q2  = fmaf(m2, s1, q2);   // s1 = exclusive cumsum(m1)
                s2 += m2;
                s1 += m1;
            }
        } else {
            #pragma unroll
            for (int r = 0; r < 4; ++r) {
                float m3 = acc[0][r], m4 = acc[1][r], m5 = acc[2][r];
                qwvu = fmaf(m5, qvu, qwvu);
                qwv  = fmaf(m5, sv, qwv);
                sw  += m5;
                qvu  = fmaf(m4, su, qvu);
                sv  += m4;
                su  += m3;
            }
        }
    };

    // ---- pipeline: 2-ahead reg prefetch, ring-3 LDS, 1 no-drain barrier/iter
    issueA(0);
    issueB(1);
    wldsA(0);

    int b0 = 0, b1 = 1, b2 = 2;   // b0 = i%3 rotating
    #pragma unroll 1
    for (int i = 0; i < NITER; i += 2) {
        if (i + 2 < NITER) issueA(i + 2);
        wldsB(b1);
        BAR();
        compute(b0);

        if (i + 3 < NITER) issueB(i + 3);
        if (i + 2 < NITER) wldsA(b2);
        BAR();
        compute(b1);

        int nb0 = b2, nb1 = b0, nb2 = b1;
        b0 = nb0; b1 = nb1; b2 = nb2;
    }

    // ---- merge the 4 lane-group stripes (time order: lg ascending) ----
    if (cg == 0) {
        #pragma unroll
        for (int m = 16; m <= 32; m <<= 1) {
            float oa0 = __shfl_xor(a0, m), os1 = __shfl_xor(s1, m);
            float os2 = __shfl_xor(s2, m), oq2 = __shfl_xor(q2, m);
            bool up = (lane & m) != 0;
            float Aa0 = up ? oa0 : a0, As1 = up ? os1 : s1;
            float As2 = up ? os2 : s2, Aq2 = up ? oq2 : q2;
            float Ba0 = up ? a0 : oa0, Bs1 = up ? s1 : os1;
            float Bs2 = up ? s2 : os2, Bq2 = up ? q2 : oq2;
            a0 = Aa0 + Ba0;
            q2 = Aq2 + Bq2 + As1 * Bs2;
            s1 = As1 + Bs1;
            s2 = As2 + Bs2;
        }
        if (lg == 0) {
            float* wp = ws + (((size_t)b * TGROUPS + tg) * F_ + f) * 10;
            wp[0] = a0; wp[1] = s1; wp[2] = s2; wp[3] = q2;
        }
    } else {
        #pragma unroll
        for (int m = 16; m <= 32; m <<= 1) {
            float osu = __shfl_xor(su, m),  osv = __shfl_xor(sv, m);
            float osw = __shfl_xor(sw, m),  oqvu = __shfl_xor(qvu, m);
            float oqwv = __shfl_xor(qwv, m), oqwvu = __shfl_xor(qwvu, m);
            bool up = (lane & m) != 0;
            float Asu = up ? osu : su,   Asv = up ? osv : sv;
            float Asw = up ? osw : sw,   Aqvu = up ? oqvu : qvu;
            float Aqwv = up ? oqwv : qwv, Aqwvu = up ? oqwvu : qwvu;
            float Bsu = up ? su : osu,   Bsv = up ? sv : osv;
            float Bsw = up ? sw : osw,   Bqvu = up ? qvu : oqvu;
            float Bqwv = up ? qwv : oqwv, Bqwvu = up ? qwvu : oqwvu;
            qwvu = Aqwvu + Bqwvu + Aqvu * Bsw + Asu * Bqwv;
            qwv  = Aqwv + Bqwv + Asv * Bsw;
            qvu  = Aqvu + Bqvu + Asu * Bsv;
            su = Asu + Bsu;
            sv = Asv + Bsv;
            sw = Asw + Bsw;
        }
        if (lg == 0) {
            float* wp = ws + (((size_t)b * TGROUPS + tg) * F_ + f) * 10;
            wp[4] = su; wp[5] = sv; wp[6] = sw;
            wp[7] = qvu; wp[8] = qwv; wp[9] = qwvu;
        }
    }
}

struct St { float a0, s1, s2, q2, su, sv, sw, qvu, qwv, qwvu; };

__device__ __forceinline__ St mergeSt(const St& A, const St& B) {
    St r;
    r.a0   = A.a0 + B.a0;
    r.q2   = A.q2 + B.q2 + A.s1 * B.s2;
    r.s1   = A.s1 + B.s1;
    r.s2   = A.s2 + B.s2;
    r.qwvu = A.qwvu + B.qwvu + A.qvu * B.sw + A.su * B.qwv;
    r.qwv  = A.qwv + B.qwv + A.sv * B.sw;
    r.qvu  = A.qvu + B.qvu + A.su * B.sv;
    r.su   = A.su + B.su;
    r.sv   = A.sv + B.sv;
    r.sw   = A.sw + B.sw;
    return r;
}

__global__ __launch_bounds__(64)
void ls2t_fold_kernel(const float* __restrict__ ws, float* __restrict__ out)
{
    const int b = blockIdx.x;
    const int f = threadIdx.x;
    St A = {0, 0, 0, 0, 0, 0, 0, 0, 0, 0};
    #pragma unroll
    for (int g = 0; g < TGROUPS; ++g) {
        const float* rp = ws + (((size_t)b * TGROUPS + g) * F_ + f) * 10;
        St r = {rp[0], rp[1], rp[2], rp[3], rp[4],
                rp[5], rp[6], rp[7], rp[8], rp[9]};
        A = mergeSt(A, r);
    }
    float* op = out + ((size_t)b * F_ + f) * 3;
    op[0] = A.a0;
    op[1] = A.q2;
    op[2] = A.qwvu;
}

extern "C" void kernel_launch(void* const* d_in, const int* in_sizes, int n_in,
                              void* d_out, int out_size, void* d_ws, size_t ws_size,
                              hipStream_t stream) {
    const float* seq  = (const float*)d_in[0];
    const float* kern = (const float*)d_in[1];
    const float* bias = (const float*)d_in[2];
    float* out = (float*)d_out;
    float* ws  = (float*)d_ws;   // B_*TGROUPS*F_*10*4 = 1.31 MB

    dim3 g1(TGROUPS, B_);        // 512 blocks
    ls2t_kernel<<<g1, TPB, 0, stream>>>(seq, kern, bias, ws);
    ls2t_fold_kernel<<<B_, F_, 0, stream>>>(ws, out);
}

// Round 6
// 45.426 us; speedup vs baseline: 1.7993x; 1.0550x over previous
//
#include <hip/hip_runtime.h>
#include <hip/hip_bf16.h>

// LS2T iterated sums (ORDER=3): B=64, T=4096, D=128, F=64, C=6.
// m_c(t,f) = seq[b,t,:]·kernel[c,:,f] + bias[c,f]
// Y1 = sum m0; Y2 = sum m2*cumx(m1); Y3 = sum m5*cumx(m4*cumx(m3))
//
// Round 6: real 3-iteration prefetch depth. 4 rotating register sets with a
// 4x-unrolled main loop (static indices); ring-4 LDS (16 KB). The ds_write
// for chunk i+1 consumes a global load issued 3 iterations earlier
// (~600-900 cyc of latency cover). No-drain barriers keep loads in flight.
// Component-split waves (cg0: c0..2 -> Y1,Y2; cg1: c3..5 -> Y3); B-frags in
// registers/AGPRs; scan chains lane-locally, one butterfly pair at the end.

#define B_ 64
#define T_ 4096
#define D_ 128
#define F_ 64
#define TGROUPS 8          // blocks per batch; each owns 512 t
#define TB 512
#define CHT 16             // t per chunk
#define NITER (TB / CHT)   // 32
#define TPB 512
#define RING 4

typedef __attribute__((ext_vector_type(8))) short short8v;
typedef __attribute__((ext_vector_type(4))) float f32x4;
typedef __attribute__((ext_vector_type(4))) unsigned short ushort4v;

__device__ __forceinline__ unsigned short bfb(float x) {
    __hip_bfloat16 h = __float2bfloat16(x);   // RNE
    unsigned short u;
    __builtin_memcpy(&u, &h, 2);
    return u;
}

// barrier WITHOUT vmcnt drain: waits only LDS ops, keeps global loads in flight
#define BAR() asm volatile("s_waitcnt lgkmcnt(0)\n\ts_barrier" ::: "memory")

__global__ __launch_bounds__(TPB, 2)
void ls2t_kernel(const float* __restrict__ seq,
                 const float* __restrict__ kern,
                 const float* __restrict__ bias,
                 float* __restrict__ ws)
{
    __shared__ unsigned short slds[RING][CHT * D_];   // 4 x 4 KB bf16

    const int tid  = threadIdx.x;
    const int tg   = blockIdx.x;
    const int b    = blockIdx.y;
    const int lane = tid & 63;
    const int w    = tid >> 6;
    const int cg   = w >> 2;       // 0 -> c0..2, 1 -> c3..5
    const int wv   = w & 3;        // f-range of this wave
    const int fr   = lane & 15;
    const int lg   = lane >> 4;
    const int f    = wv * 16 + fr;

    // ---- B fragments in registers (mfma B: col=lane&15=f, k=(lane>>4)*8+j)
    short8v bfrag[3][4];
    float bc[3];
    #pragma unroll
    for (int cc = 0; cc < 3; ++cc) {
        const int c = cg * 3 + cc;
        bc[cc] = bias[c * F_ + f];
        #pragma unroll
        for (int ks = 0; ks < 4; ++ks) {
            const float* kp = kern + ((size_t)c * D_ + ks * 32 + lg * 8) * F_ + f;
            short8v bf;
            #pragma unroll
            for (int j = 0; j < 8; ++j) bf[j] = (short)bfb(kp[(size_t)j * F_]);
            bfrag[cc][ks] = bf;
        }
    }

    const float* sbase = seq + ((size_t)b * T_ + (size_t)tg * TB) * D_;

    // staging: thread -> (row srow 0..15, float4-index c4 0..31) of the chunk.
    // chunk row r holds t_local = (r>>2)*128 + i*4 + (r&3)  (lane-group lg
    // owns contiguous t-stripe [lg*128, +128) across the 32 chunks).
    // LDS 16B block jb of row r contains global d-block (jb ^ (r&7)).
    const int srow = tid >> 5;
    const int c4   = tid & 31;
    const int skey = srow & 7;
    const float* g0 = sbase + ((size_t)((srow >> 2) * 128 + (srow & 3))) * D_ + c4 * 4;
    const int woff = srow * D_ + 8 * ((c4 >> 1) ^ skey) + 4 * (c4 & 1);  // shorts

    #define LD(i) (*reinterpret_cast<const float4*>(g0 + (size_t)(i) * 4 * D_))

    auto wst = [&](int bufi, const float4& v) {
        ushort4v u;
        u[0] = bfb(v.x); u[1] = bfb(v.y); u[2] = bfb(v.z); u[3] = bfb(v.w);
        *reinterpret_cast<ushort4v*>(&slds[bufi][woff]) = u;
    };

    // scan states (only this cg's half is live per wave)
    float a0 = 0.f, s1 = 0.f, s2 = 0.f, q2 = 0.f;
    float su = 0.f, sv = 0.f, sw = 0.f, qvu = 0.f, qwv = 0.f, qwvu = 0.f;

    auto compute = [&](int bufi) {
        f32x4 acc[3];
        #pragma unroll
        for (int cc = 0; cc < 3; ++cc)
            acc[cc] = (f32x4){bc[cc], bc[cc], bc[cc], bc[cc]};

        #pragma unroll
        for (int ks = 0; ks < 4; ++ks) {
            const int m0i = ks * 4 + lg;
            short8v a = *reinterpret_cast<const short8v*>(
                &slds[bufi][fr * D_ + 8 * (m0i ^ (fr & 7))]);
            #pragma unroll
            for (int cc = 0; cc < 3; ++cc)
                acc[cc] = __builtin_amdgcn_mfma_f32_16x16x32_bf16(
                    a, bfrag[cc][ks], acc[cc], 0, 0, 0);
        }

        // lane owns t = tg*512 + lg*128 + i*4 + r  -> chain in-lane
        if (cg == 0) {
            #pragma unroll
            for (int r = 0; r < 4; ++r) {
                float m0 = acc[0][r], m1 = acc[1][r], m2 = acc[2][r];
                a0 += m0;
                q2  = fmaf(m2, s1, q2);   // s1 = exclusive cumsum(m1)
                s2 += m2;
                s1 += m1;
            }
        } else {
            #pragma unroll
            for (int r = 0; r < 4; ++r) {
                float m3 = acc[0][r], m4 = acc[1][r], m5 = acc[2][r];
                qwvu = fmaf(m5, qvu, qwvu);
                qwv  = fmaf(m5, sv, qwv);
                sw  += m5;
                qvu  = fmaf(m4, su, qvu);
                sv  += m4;
                su  += m3;
            }
        }
    };

    // ---- pipeline: depth-3 register prefetch, ring-4 LDS, 1 barrier/iter ----
    float4 v0 = LD(0), v1 = LD(1), v2 = LD(2), v3 = LD(3);
    wst(0, v0);
    BAR();

    #pragma unroll 1
    for (int g = 0; g < 7; ++g) {
        const int i = g * 4;
        // slot 0: compute chunk i
        v0 = LD(i + 4);
        wst(1, v1);            // chunk i+1 (loaded 3 iters ago)
        BAR();
        compute(0);
        // slot 1: compute chunk i+1
        v1 = LD(i + 5);
        wst(2, v2);
        BAR();
        compute(1);
        // slot 2
        v2 = LD(i + 6);
        wst(3, v3);
        BAR();
        compute(2);
        // slot 3
        v3 = LD(i + 7);
        wst(0, v0);            // chunk i+4
        BAR();
        compute(3);
    }
    // epilogue: chunks 28..31 (v0..v3 hold 28..31; buf0 already has 28)
    wst(1, v1); BAR(); compute(0);
    wst(2, v2); BAR(); compute(1);
    wst(3, v3); BAR(); compute(2);
    compute(3);

    // ---- merge the 4 lane-group stripes (time order: lg ascending) ----
    if (cg == 0) {
        #pragma unroll
        for (int m = 16; m <= 32; m <<= 1) {
            float oa0 = __shfl_xor(a0, m), os1 = __shfl_xor(s1, m);
            float os2 = __shfl_xor(s2, m), oq2 = __shfl_xor(q2, m);
            bool up = (lane & m) != 0;
            float Aa0 = up ? oa0 : a0, As1 = up ? os1 : s1;
            float As2 = up ? os2 : s2, Aq2 = up ? oq2 : q2;
            float Ba0 = up ? a0 : oa0, Bs1 = up ? s1 : os1;
            float Bs2 = up ? s2 : os2, Bq2 = up ? q2 : oq2;
            a0 = Aa0 + Ba0;
            q2 = Aq2 + Bq2 + As1 * Bs2;
            s1 = As1 + Bs1;
            s2 = As2 + Bs2;
        }
        if (lg == 0) {
            float* wp = ws + (((size_t)b * TGROUPS + tg) * F_ + f) * 10;
            wp[0] = a0; wp[1] = s1; wp[2] = s2; wp[3] = q2;
        }
    } else {
        #pragma unroll
        for (int m = 16; m <= 32; m <<= 1) {
            float osu = __shfl_xor(su, m),  osv = __shfl_xor(sv, m);
            float osw = __shfl_xor(sw, m),  oqvu = __shfl_xor(qvu, m);
            float oqwv = __shfl_xor(qwv, m), oqwvu = __shfl_xor(qwvu, m);
            bool up = (lane & m) != 0;
            float Asu = up ? osu : su,   Asv = up ? osv : sv;
            float Asw = up ? osw : sw,   Aqvu = up ? oqvu : qvu;
            float Aqwv = up ? oqwv : qwv, Aqwvu = up ? oqwvu : qwvu;
            float Bsu = up ? su : osu,   Bsv = up ? sv : osv;
            float Bsw = up ? sw : osw,   Bqvu = up ? qvu : oqvu;
            float Bqwv = up ? qwv : oqwv, Bqwvu = up ? qwvu : oqwvu;
            qwvu = Aqwvu + Bqwvu + Aqvu * Bsw + Asu * Bqwv;
            qwv  = Aqwv + Bqwv + Asv * Bsw;
            qvu  = Aqvu + Bqvu + Asu * Bsv;
            su = Asu + Bsu;
            sv = Asv + Bsv;
            sw = Asw + Bsw;
        }
        if (lg == 0) {
            float* wp = ws + (((size_t)b * TGROUPS + tg) * F_ + f) * 10;
            wp[4] = su; wp[5] = sv; wp[6] = sw;
            wp[7] = qvu; wp[8] = qwv; wp[9] = qwvu;
        }
    }
    #undef LD
}

struct St { float a0, s1, s2, q2, su, sv, sw, qvu, qwv, qwvu; };

__device__ __forceinline__ St mergeSt(const St& A, const St& B) {
    St r;
    r.a0   = A.a0 + B.a0;
    r.q2   = A.q2 + B.q2 + A.s1 * B.s2;
    r.s1   = A.s1 + B.s1;
    r.s2   = A.s2 + B.s2;
    r.qwvu = A.qwvu + B.qwvu + A.qvu * B.sw + A.su * B.qwv;
    r.qwv  = A.qwv + B.qwv + A.sv * B.sw;
    r.qvu  = A.qvu + B.qvu + A.su * B.sv;
    r.su   = A.su + B.su;
    r.sv   = A.sv + B.sv;
    r.sw   = A.sw + B.sw;
    return r;
}

__global__ __launch_bounds__(64)
void ls2t_fold_kernel(const float* __restrict__ ws, float* __restrict__ out)
{
    const int b = blockIdx.x;
    const int f = threadIdx.x;
    St A = {0, 0, 0, 0, 0, 0, 0, 0, 0, 0};
    #pragma unroll
    for (int g = 0; g < TGROUPS; ++g) {
        const float* rp = ws + (((size_t)b * TGROUPS + g) * F_ + f) * 10;
        St r = {rp[0], rp[1], rp[2], rp[3], rp[4],
                rp[5], rp[6], rp[7], rp[8], rp[9]};
        A = mergeSt(A, r);
    }
    float* op = out + ((size_t)b * F_ + f) * 3;
    op[0] = A.a0;
    op[1] = A.q2;
    op[2] = A.qwvu;
}

extern "C" void kernel_launch(void* const* d_in, const int* in_sizes, int n_in,
                              void* d_out, int out_size, void* d_ws, size_t ws_size,
                              hipStream_t stream) {
    const float* seq  = (const float*)d_in[0];
    const float* kern = (const float*)d_in[1];
    const float* bias = (const float*)d_in[2];
    float* out = (float*)d_out;
    float* ws  = (float*)d_ws;   // B_*TGROUPS*F_*10*4 = 1.31 MB

    dim3 g1(TGROUPS, B_);        // 512 blocks, 2 per CU
    ls2t_kernel<<<g1, TPB, 0, stream>>>(seq, kern, bias, ws);
    ls2t_fold_kernel<<<B_, F_, 0, stream>>>(ws, out);
}